// Round 3
// baseline (9179.049 us; speedup 1.0000x reference)
//
#include <hip/hip_runtime.h>
#include <math.h>

// Problem constants (fixed shapes from the reference)
#define BB 32
#define SS 256
#define EE 300
#define EP 304          // E padded to multiple of 16
#define HH 256
#define TT 19           // NUM_TAGS + START + STOP
#define START_TAG 17
#define STOP_TAG 18
#define BS 8192         // B*S
#define GIN_PER_DIR (8192*1024)

__device__ __forceinline__ float sigm(float x){ return 1.0f/(1.0f+expf(-x)); }

// ---------------- ws layout (float offsets) ----------------
// x_pad : [BS][304]            off 0          size 2490368
// WT    : [304][2048]          off 2490368    size 622592   (transposed+padded, COLUMNS PERMUTED to interleaved (j*4+g))
// bias2 : [2048]               off 3112960    size 2048     (bih+bhh, same permuted order)
// Wq    : [2][64 q][1024 tid]  off 3115008    size 524288   (Whh packed for k-split-4 lstm, float4 elements)
// gin   : [2][BS][1024]        off 3639296    size 16777216 (preacts, interleaved: row j*4+g)
// hseq  : [BS][512]            off 20416512   size 4194304  (concat hf|hb)
// emit  : [BS][19]             off 24610816   size 155648
// ptr   : [BS][19] (int)       off 24766464   size 155648
// nll   : [32]                 off 24922112

// -------- embed gather + mask, pad E to 304 with zeros --------
__global__ void k_embed(const int* __restrict__ wi, const int* __restrict__ msk,
                        const float* __restrict__ emb, float* __restrict__ x){
  int id = blockIdx.x*256 + threadIdx.x;        // BS*76 float4 slots
  if (id >= BS*76) return;
  int row = id / 76, q = id - row*76;
  float4 v = make_float4(0.f,0.f,0.f,0.f);
  if (q < 75){                                   // 75*4 = 300 real elements
    const float4* e4 = (const float4*)emb;       // emb rows are 1200B = 16B aligned
    v = e4[(size_t)wi[row]*75 + q];
    float m = (float)msk[row];
    v.x*=m; v.y*=m; v.z*=m; v.w*=m;
  }
  ((float4*)x)[(size_t)row*76 + q] = v;
}

// -------- transpose Wih into WT[304][2048] with PERMUTED columns, build bias --------
// column n: dd = n>>10 (dir), r = n&1023, j = r>>2 (h-row), g = r&3 (gate)
// original gate row = g*256 + j. So gin comes out interleaved (i,f,g,o per h-row).
__global__ void k_prep_wt(const float* __restrict__ Wih_f, const float* __restrict__ Wih_b,
                          const float* __restrict__ bih_f, const float* __restrict__ bhh_f,
                          const float* __restrict__ bih_b, const float* __restrict__ bhh_b,
                          float* __restrict__ WT, float* __restrict__ bias){
  int id = blockIdx.x*256 + threadIdx.x;
  if (id < 304*2048){
    int k = id >> 11, n = id & 2047;
    int dd = n >> 10, r = n & 1023, j = r >> 2, g = r & 3;
    int orow = g*256 + j;
    float v = 0.f;
    if (k < 300) v = dd ? Wih_b[orow*300 + k] : Wih_f[orow*300 + k];
    WT[id] = v;
  } else {
    int n = id - 304*2048;
    if (n < 2048){
      int dd = n >> 10, r = n & 1023, j = r >> 2, g = r & 3;
      int orow = g*256 + j;
      bias[n] = dd ? (bih_b[orow] + bhh_b[orow]) : (bih_f[orow] + bhh_f[orow]);
    }
  }
}

// -------- pack Whh for k-split-4 lstm --------
// thread tid = kpart*256 + urow; q = jj*4 + g (jj in [0,16))
// Wq[d][q][tid] = float4( Whh_d[g*256+urow][ (kpart*16 + jj)*4 .. +3 ] )
__global__ void k_prep_whh(const float* __restrict__ Whh_f, const float* __restrict__ Whh_b,
                           float4* __restrict__ Wq){
  int d = blockIdx.y;
  int id = blockIdx.x*256 + threadIdx.x;        // < 65536 per dir
  const float4* W = (const float4*)(d ? Whh_b : Whh_f);   // [1024 rows][64 f4]
  int tid = id & 1023, q = id >> 10;
  int kpart = tid >> 8, urow = tid & 255;
  int jj = q >> 2, g = q & 3;
  Wq[(size_t)d*65536 + (size_t)q*1024 + tid] = W[(size_t)(g*256 + urow)*64 + kpart*16 + jj];
}

// -------- input-gate GEMM: gin[dd][row][r] = x @ WT[:,n] + bias[n] (columns pre-permuted) --------
__global__ __launch_bounds__(256) void k_gemm(const float* __restrict__ x,
      const float* __restrict__ WT, const float* __restrict__ bias,
      float* __restrict__ gin){
  __shared__ float As[16][65];
  __shared__ float Bs[16][64];
  int tid = threadIdx.x;
  int tx = tid & 15, ty = tid >> 4;
  int n0 = blockIdx.x * 64, m0 = blockIdx.y * 64;
  float acc[4][4] = {};
  for (int kt = 0; kt < 19; ++kt){
    int k0 = kt*16;
    #pragma unroll
    for (int i = 0; i < 4; ++i){
      int idx = tid + i*256;
      int ak = idx & 15, am = idx >> 4;
      As[ak][am] = x[(size_t)(m0+am)*304 + (k0+ak)];
      int bn = idx & 63, bk = idx >> 6;
      Bs[bk][bn] = WT[(size_t)(k0+bk)*2048 + (n0+bn)];
    }
    __syncthreads();
    #pragma unroll
    for (int k = 0; k < 16; ++k){
      float a0 = As[k][ty*4+0], a1 = As[k][ty*4+1], a2 = As[k][ty*4+2], a3 = As[k][ty*4+3];
      float b0 = Bs[k][tx*4+0], b1 = Bs[k][tx*4+1], b2 = Bs[k][tx*4+2], b3 = Bs[k][tx*4+3];
      acc[0][0]+=a0*b0; acc[0][1]+=a0*b1; acc[0][2]+=a0*b2; acc[0][3]+=a0*b3;
      acc[1][0]+=a1*b0; acc[1][1]+=a1*b1; acc[1][2]+=a1*b2; acc[1][3]+=a1*b3;
      acc[2][0]+=a2*b0; acc[2][1]+=a2*b1; acc[2][2]+=a2*b2; acc[2][3]+=a2*b3;
      acc[3][0]+=a3*b0; acc[3][1]+=a3*b1; acc[3][2]+=a3*b2; acc[3][3]+=a3*b3;
    }
    __syncthreads();
  }
  #pragma unroll
  for (int i = 0; i < 4; ++i){
    int m = m0 + ty*4 + i;
    #pragma unroll
    for (int j = 0; j < 4; ++j){
      int n = n0 + tx*4 + j;
      int dd = n >> 10, r = n & 1023;
      gin[(size_t)dd*GIN_PER_DIR + (size_t)m*1024 + r] = acc[i][j] + bias[n];
    }
  }
}

// -------- BiLSTM recurrence v3: one WG of 1024 per (batch, dir), k-split 4 --------
// thread (kpart=tid>>8, urow=tid&255): 4 gate-partials of h-row urow over 64 k's.
// h reads wave-uniform (16/thread/step); weights 8-deep software pipeline from L2.
__global__ __launch_bounds__(1024) void k_lstm(const float* __restrict__ gin,
                 const float4* __restrict__ Wq, float* __restrict__ hseq){
  int tid = threadIdx.x;
  int b = blockIdx.x & 31, d = blockIdx.x >> 5;
  int kpart = tid >> 8;
  const float* gb = gin + (size_t)d*GIN_PER_DIR + (size_t)b*SS*1024;
  const float4* wq = Wq + (size_t)d*65536 + tid;   // + q*1024 per q
  __shared__ float hs[256];
  __shared__ float4 gl4[1024];
  float c = 0.f;
  if (tid < 256) hs[tid] = 0.f;
  __syncthreads();
  const float4* hs4 = (const float4*)hs;
  for (int s = 0; s < SS; ++s){
    int t = d ? (SS-1-s) : s;
    float4 gv = make_float4(0.f,0.f,0.f,0.f);
    if (tid < 256) gv = ((const float4*)(gb + (size_t)t*1024))[tid];  // prefetch, hides under k-loop
    float ai = 0.f, af = 0.f, ag = 0.f, ao = 0.f;
    float4 buf[8];
    #pragma unroll
    for (int i = 0; i < 8; ++i) buf[i] = wq[i*1024];
    #pragma unroll
    for (int jj = 0; jj < 16; jj += 2){
      #pragma unroll
      for (int u = 0; u < 2; ++u){
        float4 h4 = hs4[kpart*16 + jj + u];
        #pragma unroll
        for (int g = 0; g < 4; ++g){
          float4 w = buf[u*4 + g];
          if (jj + 2 < 16) buf[u*4 + g] = wq[((jj + 2 + u)*4 + g)*1024];  // refill after use
          float dp = w.x*h4.x + w.y*h4.y + w.z*h4.z + w.w*h4.w;
          if      (g == 0) ai += dp;
          else if (g == 1) af += dp;
          else if (g == 2) ag += dp;
          else             ao += dp;
        }
      }
    }
    gl4[tid] = make_float4(ai, af, ag, ao);
    __syncthreads();
    if (tid < 256){
      float4 p0 = gl4[tid], p1 = gl4[256+tid], p2 = gl4[512+tid], p3 = gl4[768+tid];
      float iv = sigm (p0.x + p1.x + p2.x + p3.x + gv.x);
      float fv = sigm (p0.y + p1.y + p2.y + p3.y + gv.y);
      float gg = tanhf(p0.z + p1.z + p2.z + p3.z + gv.z);
      float ov = sigm (p0.w + p1.w + p2.w + p3.w + gv.w);
      c = fv*c + iv*gg;
      float hv = ov*tanhf(c);
      hs[tid] = hv;
      hseq[((size_t)(b*SS + t))*512 + d*256 + tid] = hv;
    }
    __syncthreads();
  }
}

// -------- tag logits: emit[row][t] = hseq[row] . W_tag[t] + b_tag[t] --------
__global__ void k_emit(const float* __restrict__ hseq, const float* __restrict__ Wtag,
                       const float* __restrict__ btag, float* __restrict__ emit){
  int id = blockIdx.x*256 + threadIdx.x;
  if (id >= BS*TT) return;
  int row = id / TT, tg = id - row*TT;
  const float4* hp = (const float4*)(hseq + (size_t)row*512);
  const float4* wp = (const float4*)(Wtag + (size_t)tg*512);
  float acc = btag[tg];
  #pragma unroll 8
  for (int k = 0; k < 128; ++k){
    float4 h = hp[k], w = wp[k];
    acc += h.x*w.x + h.y*w.y + h.z*w.z + h.w*w.w;
  }
  emit[id] = acc;
}

// -------- CRF NLL (forward algorithm + gold score), one wave per batch --------
__global__ void k_crf(const float* __restrict__ emit, const int* __restrict__ msk,
                      const int* __restrict__ lab, const float* __restrict__ trans,
                      float* __restrict__ nll){
  int b = blockIdx.x, tid = threadIdx.x;
  __shared__ float tr[361];
  __shared__ float al[19];
  for (int i = tid; i < 361; i += 64) tr[i] = trans[i];
  const float* eb = emit + (size_t)b*SS*TT;
  const int* mb = msk + b*SS;
  const int* lb = lab + b*SS;
  __syncthreads();
  float gp = 0.f; int ln = 0;
  for (int t = tid; t < SS; t += 64){
    int m = mb[t];
    ln += m;
    if (m){
      int l = lb[t];
      int p = t ? lb[t-1] : START_TAG;
      gp += tr[p*19 + l] + eb[t*19 + l];
    }
  }
  for (int off = 32; off; off >>= 1){ gp += __shfl_down(gp, off); ln += __shfl_down(ln, off); }
  float gold = 0.f;
  if (tid == 0){
    int lt = lb[ln - 1];
    gold = gp + tr[lt*19 + STOP_TAG];
  }
  if (tid < 19) al[tid] = eb[tid] + tr[START_TAG*19 + tid];
  __syncthreads();
  for (int t = 1; t < SS; ++t){
    int m = mb[t];
    float nv = 0.f;
    if (tid < 19){
      float mx = -1e30f;
      for (int p = 0; p < 19; ++p){ float v = al[p] + tr[p*19 + tid]; mx = fmaxf(mx, v); }
      float sum = 0.f;
      for (int p = 0; p < 19; ++p) sum += expf(al[p] + tr[p*19 + tid] - mx);
      nv = mx + logf(sum) + eb[t*19 + tid];
    }
    __syncthreads();
    if (tid < 19 && m) al[tid] = nv;
    __syncthreads();
  }
  if (tid == 0){
    float mx = -1e30f;
    for (int c2 = 0; c2 < 19; ++c2) mx = fmaxf(mx, al[c2] + tr[c2*19 + STOP_TAG]);
    float sum = 0.f;
    for (int c2 = 0; c2 < 19; ++c2) sum += expf(al[c2] + tr[c2*19 + STOP_TAG] - mx);
    nll[b] = (mx + logf(sum)) - gold;
  }
}

// -------- Viterbi decode, one wave per batch; writes tags (as float) to d_out[1..] --------
__global__ void k_vit(const float* __restrict__ emit, const int* __restrict__ msk,
                      const float* __restrict__ trans, int* __restrict__ ptr,
                      float* __restrict__ out){
  int b = blockIdx.x, tid = threadIdx.x;
  __shared__ float tr[361];
  __shared__ float dl[19];
  __shared__ int tg[256];
  for (int i = tid; i < 361; i += 64) tr[i] = trans[i];
  const float* eb = emit + (size_t)b*SS*TT;
  const int* mb = msk + b*SS;
  int* pb = ptr + (size_t)b*SS*TT;
  if (tid < 19) dl[tid] = eb[tid] + tr[START_TAG*19 + tid];
  __syncthreads();
  for (int t = 1; t < SS; ++t){
    int m = mb[t];
    float best = -1e30f; int bp = 0;
    if (tid < 19){
      for (int p = 0; p < 19; ++p){
        float v = dl[p] + tr[p*19 + tid];
        if (v > best){ best = v; bp = p; }       // strict > == first-max (jnp.argmax)
      }
    }
    __syncthreads();
    if (tid < 19){
      if (m){ dl[tid] = best + eb[t*19 + tid]; pb[t*19 + tid] = bp; }
      else  { pb[t*19 + tid] = tid; }            // identity pass-through when padded
    }
    __syncthreads();
  }
  if (tid == 0){
    float bv = -1e30f; int bl = 0;
    for (int c2 = 0; c2 < 19; ++c2){
      float v = dl[c2] + tr[c2*19 + STOP_TAG];
      if (v > bv){ bv = v; bl = c2; }
    }
    tg[SS-1] = bl;
    for (int t = SS-1; t > 0; --t) tg[t-1] = pb[t*19 + tg[t]];
  }
  __syncthreads();
  for (int t = tid; t < SS; t += 64)
    out[1 + b*SS + t] = (float)(tg[t] * mb[t]);
}

// -------- final loss reduce: d_out[0] = sum(nll)/B --------
__global__ void k_final(const float* __restrict__ nll, float* __restrict__ out){
  int tid = threadIdx.x;
  float v = (tid < 32) ? nll[tid] : 0.f;
  for (int off = 32; off; off >>= 1) v += __shfl_down(v, off);
  if (tid == 0) out[0] = v * (1.0f/32.0f);
}

extern "C" void kernel_launch(void* const* d_in, const int* in_sizes, int n_in,
                              void* d_out, int out_size, void* d_ws, size_t ws_size,
                              hipStream_t stream){
  const int*   wi    = (const int*)d_in[0];
  const int*   msk   = (const int*)d_in[1];
  const int*   lab   = (const int*)d_in[2];
  // d_in[3] labels_token, d_in[4] data_type: unused (data_type==1 branch)
  const float* emb   = (const float*)d_in[5];
  const float* Wih_f = (const float*)d_in[6];
  const float* Whh_f = (const float*)d_in[7];
  const float* bih_f = (const float*)d_in[8];
  const float* bhh_f = (const float*)d_in[9];
  const float* Wih_b = (const float*)d_in[10];
  const float* Whh_b = (const float*)d_in[11];
  const float* bih_b = (const float*)d_in[12];
  const float* bhh_b = (const float*)d_in[13];
  const float* Wtag  = (const float*)d_in[14];
  const float* btag  = (const float*)d_in[15];
  const float* trans = (const float*)d_in[16];

  float* ws   = (float*)d_ws;
  float* x    = ws;
  float* WT   = ws + 2490368;
  float* bias = ws + 3112960;
  float4* Wq  = (float4*)(ws + 3115008);
  float* gin  = ws + 3639296;
  float* hseq = ws + 20416512;
  float* emit = ws + 24610816;
  int*   ptr  = (int*)(ws + 24766464);
  float* nll  = ws + 24922112;
  float* out  = (float*)d_out;

  hipLaunchKernelGGL(k_embed,    dim3(2432),    dim3(256),  0, stream, wi, msk, emb, x);
  hipLaunchKernelGGL(k_prep_wt,  dim3(2440),    dim3(256),  0, stream,
                     Wih_f, Wih_b, bih_f, bhh_f, bih_b, bhh_b, WT, bias);
  hipLaunchKernelGGL(k_prep_whh, dim3(256,2),   dim3(256),  0, stream, Whh_f, Whh_b, Wq);
  hipLaunchKernelGGL(k_gemm,     dim3(32,128),  dim3(256),  0, stream, x, WT, bias, gin);
  hipLaunchKernelGGL(k_lstm,     dim3(64),      dim3(1024), 0, stream, gin, Wq, hseq);
  hipLaunchKernelGGL(k_emit,     dim3(608),     dim3(256),  0, stream, hseq, Wtag, btag, emit);
  hipLaunchKernelGGL(k_crf,      dim3(32),      dim3(64),   0, stream, emit, msk, lab, trans, nll);
  hipLaunchKernelGGL(k_vit,      dim3(32),      dim3(64),   0, stream, emit, msk, trans, ptr, out);
  hipLaunchKernelGGL(k_final,    dim3(1),       dim3(64),   0, stream, nll, out);
}

// Round 4
// 3665.851 us; speedup vs baseline: 2.5039x; 2.5039x over previous
//
#include <hip/hip_runtime.h>
#include <math.h>

// Problem constants (fixed shapes from the reference)
#define BB 32
#define SS 256
#define EE 300
#define EP 304          // E padded to multiple of 16
#define HH 256
#define TT 19           // NUM_TAGS + START + STOP
#define START_TAG 17
#define STOP_TAG 18
#define BS 8192         // B*S
#define GIN_PER_DIR (8192*1024)

__device__ __forceinline__ float sigm(float x){ return 1.0f/(1.0f+expf(-x)); }
__device__ __forceinline__ float dot4(float4 a, float4 b){
  return a.x*b.x + a.y*b.y + a.z*b.z + a.w*b.w;
}

// ---------------- ws layout (float offsets) ----------------
// x_pad : [BS][304]            off 0          size 2490368
//   (xbuf/flags live INSIDE x_pad region — x is dead after k_gemm)
//   xbuf : [2 par][64 bd][4 q][64]  off 2097152  size 32768
//   flags: [64 bd][4 q] int         off 2129920  size 256
// WT    : [304][2048]          off 2490368    size 622592   (transposed+padded, cols permuted to (j*4+g))
// bias2 : [2048]               off 3112960    size 2048
// Wr    : packed Whh reg tiles off 3115008    size 524288   (2 MB, see k_prep_wreg)
// gin   : [2][BS][1024]        off 3639296    size 16777216 (preacts, interleaved row j*4+g)
// hseq  : [BS][512]            off 20416512   size 4194304
// emit  : [BS][19]             off 24610816   size 155648
// ptr   : [BS][19] (int)       off 24766464   size 155648
// nll   : [32]                 off 24922112

// -------- embed gather + mask, pad E to 304 with zeros --------
__global__ void k_embed(const int* __restrict__ wi, const int* __restrict__ msk,
                        const float* __restrict__ emb, float* __restrict__ x){
  int id = blockIdx.x*256 + threadIdx.x;        // BS*76 float4 slots
  if (id >= BS*76) return;
  int row = id / 76, q = id - row*76;
  float4 v = make_float4(0.f,0.f,0.f,0.f);
  if (q < 75){                                   // 75*4 = 300 real elements
    const float4* e4 = (const float4*)emb;       // emb rows are 1200B = 16B aligned
    v = e4[(size_t)wi[row]*75 + q];
    float m = (float)msk[row];
    v.x*=m; v.y*=m; v.z*=m; v.w*=m;
  }
  ((float4*)x)[(size_t)row*76 + q] = v;
}

// -------- transpose Wih into WT[304][2048] with PERMUTED columns, build bias --------
// column n: dd = n>>10 (dir), r = n&1023, j = r>>2 (h-row), g = r&3 (gate)
__global__ void k_prep_wt(const float* __restrict__ Wih_f, const float* __restrict__ Wih_b,
                          const float* __restrict__ bih_f, const float* __restrict__ bhh_f,
                          const float* __restrict__ bih_b, const float* __restrict__ bhh_b,
                          float* __restrict__ WT, float* __restrict__ bias){
  int id = blockIdx.x*256 + threadIdx.x;
  if (id < 304*2048){
    int k = id >> 11, n = id & 2047;
    int dd = n >> 10, r = n & 1023, j = r >> 2, g = r & 3;
    int orow = g*256 + j;
    float v = 0.f;
    if (k < 300) v = dd ? Wih_b[orow*300 + k] : Wih_f[orow*300 + k];
    WT[id] = v;
  } else {
    int n = id - 304*2048;
    if (n < 2048){
      int dd = n >> 10, r = n & 1023, j = r >> 2, g = r & 3;
      int orow = g*256 + j;
      bias[n] = dd ? (bih_b[orow] + bhh_b[orow]) : (bih_f[orow] + bhh_f[orow]);
    }
  }
}

// -------- pack Whh into per-thread register tiles --------
// Wr[ (((d*4+q)*16 + kblk)*16 + i)*64 + lane ], i = g*4 + kq
//   = float4( Whh_d[g*256 + q*64 + lane][ kblk*16 + kq*4 .. +3 ] )
__global__ void k_prep_wreg(const float* __restrict__ Whh_f, const float* __restrict__ Whh_b,
                            float4* __restrict__ Wr){
  int id = blockIdx.x*256 + threadIdx.x;        // 131072 float4 total
  int lane = id & 63;
  int i    = (id >> 6) & 15;
  int kblk = (id >> 10) & 15;
  int q    = (id >> 14) & 3;
  int d    = id >> 16;
  int g = i >> 2, kq = i & 3;
  const float4* W4 = (const float4*)(d ? Whh_b : Whh_f);  // [1024 rows][64 f4]
  Wr[id] = W4[(size_t)(g*256 + q*64 + lane)*64 + kblk*4 + kq];
}

// -------- input-gate GEMM: gin[dd][row][r] = x @ WT[:,n] + bias[n] --------
__global__ __launch_bounds__(256) void k_gemm(const float* __restrict__ x,
      const float* __restrict__ WT, const float* __restrict__ bias,
      float* __restrict__ gin){
  __shared__ float As[16][65];
  __shared__ float Bs[16][64];
  int tid = threadIdx.x;
  int tx = tid & 15, ty = tid >> 4;
  int n0 = blockIdx.x * 64, m0 = blockIdx.y * 64;
  float acc[4][4] = {};
  for (int kt = 0; kt < 19; ++kt){
    int k0 = kt*16;
    #pragma unroll
    for (int i = 0; i < 4; ++i){
      int idx = tid + i*256;
      int ak = idx & 15, am = idx >> 4;
      As[ak][am] = x[(size_t)(m0+am)*304 + (k0+ak)];
      int bn = idx & 63, bk = idx >> 6;
      Bs[bk][bn] = WT[(size_t)(k0+bk)*2048 + (n0+bn)];
    }
    __syncthreads();
    #pragma unroll
    for (int k = 0; k < 16; ++k){
      float a0 = As[k][ty*4+0], a1 = As[k][ty*4+1], a2 = As[k][ty*4+2], a3 = As[k][ty*4+3];
      float b0 = Bs[k][tx*4+0], b1 = Bs[k][tx*4+1], b2 = Bs[k][tx*4+2], b3 = Bs[k][tx*4+3];
      acc[0][0]+=a0*b0; acc[0][1]+=a0*b1; acc[0][2]+=a0*b2; acc[0][3]+=a0*b3;
      acc[1][0]+=a1*b0; acc[1][1]+=a1*b1; acc[1][2]+=a1*b2; acc[1][3]+=a1*b3;
      acc[2][0]+=a2*b0; acc[2][1]+=a2*b1; acc[2][2]+=a2*b2; acc[2][3]+=a2*b3;
      acc[3][0]+=a3*b0; acc[3][1]+=a3*b1; acc[3][2]+=a3*b2; acc[3][3]+=a3*b3;
    }
    __syncthreads();
  }
  #pragma unroll
  for (int i = 0; i < 4; ++i){
    int m = m0 + ty*4 + i;
    #pragma unroll
    for (int j = 0; j < 4; ++j){
      int n = n0 + tx*4 + j;
      int dd = n >> 10, r = n & 1023;
      gin[(size_t)dd*GIN_PER_DIR + (size_t)m*1024 + r] = acc[i][j] + bias[n];
    }
  }
}

// -------- BiLSTM recurrence v4: register-resident weights, 4 WGs per (b,d) --------
// blockIdx = q*64 + bd  (siblings q=0..3 of one bd land on the same XCD mod-8).
// Thread (kblk=tid>>6, lane=tid&63): 4 gate partials of h-row (q*64+lane) over
// k in [kblk*16, kblk*16+16), weights in 16 float4 registers (loaded once).
// Cross-WG h exchange via agent-scope atomics, double-buffered by step parity.
__global__ __launch_bounds__(1024) void k_lstm(const float* __restrict__ gin,
                 const float4* __restrict__ Wr, float* __restrict__ hseq,
                 float* __restrict__ xbuf, int* __restrict__ flags){
  int tid = threadIdx.x;
  int bd = blockIdx.x & 63;
  int q  = blockIdx.x >> 6;
  int b = bd & 31, d = bd >> 5;
  int kblk = tid >> 6, lane = tid & 63;

  // load persistent weight tile: 16 float4 = 64 VGPRs
  const float4* wp = Wr + ((size_t)((d*4 + q)*16 + kblk)*16)*64 + lane;
  float4 w[16];
  #pragma unroll
  for (int i = 0; i < 16; ++i) w[i] = wp[i*64];

  const float* gb = gin + (size_t)d*GIN_PER_DIR + (size_t)b*SS*1024 + q*256;
  __shared__ float hs[256];        // full h(t-1)
  __shared__ float4 gl4[1024];     // partials [kblk][lane]
  if (tid < 256) hs[tid] = 0.f;
  float c = 0.f;
  int sib0 = (q+1)&3, sib1 = (q+2)&3, sib2 = (q+3)&3;
  __syncthreads();

  for (int s = 0; s < SS; ++s){
    int t = d ? (SS-1-s) : s;
    float4 gv = make_float4(0.f,0.f,0.f,0.f);
    if (tid < 64) gv = ((const float4*)(gb + (size_t)t*1024))[tid];  // prefetch own gin rows
    const float4* hs4 = (const float4*)hs;
    float4 h0 = hs4[kblk*4+0], h1 = hs4[kblk*4+1], h2 = hs4[kblk*4+2], h3 = hs4[kblk*4+3];
    float pi = dot4(w[0],h0)+dot4(w[1],h1)+dot4(w[2],h2)+dot4(w[3],h3);
    float pf = dot4(w[4],h0)+dot4(w[5],h1)+dot4(w[6],h2)+dot4(w[7],h3);
    float pg = dot4(w[8],h0)+dot4(w[9],h1)+dot4(w[10],h2)+dot4(w[11],h3);
    float po = dot4(w[12],h0)+dot4(w[13],h1)+dot4(w[14],h2)+dot4(w[15],h3);
    gl4[kblk*64 + lane] = make_float4(pi,pf,pg,po);
    __syncthreads();
    if (tid < 64){
      float4 sa = gv;
      #pragma unroll
      for (int k = 0; k < 16; ++k){
        float4 p = gl4[k*64 + tid];
        sa.x += p.x; sa.y += p.y; sa.z += p.z; sa.w += p.w;
      }
      float iv = sigm(sa.x), fv = sigm(sa.y), gg = tanhf(sa.z), ov = sigm(sa.w);
      c = fv*c + iv*gg;
      float hv = ov*tanhf(c);
      hs[q*64 + tid] = hv;
      hseq[((size_t)(b*SS + t))*512 + d*256 + q*64 + tid] = hv;
      // publish own quarter (agent-scope so siblings on any XCD see it)
      __hip_atomic_store(&xbuf[(((size_t)(s&1)*64 + bd)*4 + q)*64 + tid], hv,
                         __ATOMIC_RELAXED, __HIP_MEMORY_SCOPE_AGENT);
    }
    if (s == SS-1) break;                        // last h needs no exchange
    if (tid < 64){
      __threadfence();                           // drain wave's stores to coherence point
      if (tid == 0)
        __hip_atomic_store(&flags[bd*4 + q], s+1,
                           __ATOMIC_RELEASE, __HIP_MEMORY_SCOPE_AGENT);
    }
    if (tid < 3){
      int sq = (tid == 0) ? sib0 : (tid == 1) ? sib1 : sib2;
      while (__hip_atomic_load(&flags[bd*4 + sq],
                               __ATOMIC_ACQUIRE, __HIP_MEMORY_SCOPE_AGENT) <= s)
        __builtin_amdgcn_s_sleep(1);
    }
    __syncthreads();
    if (tid < 256 && (tid >> 6) != q){
      hs[tid] = __hip_atomic_load(&xbuf[(((size_t)(s&1)*64 + bd)*4 + (tid>>6))*64 + (tid&63)],
                                  __ATOMIC_RELAXED, __HIP_MEMORY_SCOPE_AGENT);
    }
    __syncthreads();
  }
}

// -------- tag logits: emit[row][t] = hseq[row] . W_tag[t] + b_tag[t] --------
__global__ void k_emit(const float* __restrict__ hseq, const float* __restrict__ Wtag,
                       const float* __restrict__ btag, float* __restrict__ emit){
  int id = blockIdx.x*256 + threadIdx.x;
  if (id >= BS*TT) return;
  int row = id / TT, tg = id - row*TT;
  const float4* hp = (const float4*)(hseq + (size_t)row*512);
  const float4* wp = (const float4*)(Wtag + (size_t)tg*512);
  float acc = btag[tg];
  #pragma unroll 8
  for (int k = 0; k < 128; ++k){
    float4 h = hp[k], w = wp[k];
    acc += h.x*w.x + h.y*w.y + h.z*w.z + h.w*w.w;
  }
  emit[id] = acc;
}

// -------- CRF NLL (forward algorithm + gold score), one wave per batch --------
__global__ void k_crf(const float* __restrict__ emit, const int* __restrict__ msk,
                      const int* __restrict__ lab, const float* __restrict__ trans,
                      float* __restrict__ nll){
  int b = blockIdx.x, tid = threadIdx.x;
  __shared__ float tr[361];
  __shared__ float al[19];
  for (int i = tid; i < 361; i += 64) tr[i] = trans[i];
  const float* eb = emit + (size_t)b*SS*TT;
  const int* mb = msk + b*SS;
  const int* lb = lab + b*SS;
  __syncthreads();
  float gp = 0.f; int ln = 0;
  for (int t = tid; t < SS; t += 64){
    int m = mb[t];
    ln += m;
    if (m){
      int l = lb[t];
      int p = t ? lb[t-1] : START_TAG;
      gp += tr[p*19 + l] + eb[t*19 + l];
    }
  }
  for (int off = 32; off; off >>= 1){ gp += __shfl_down(gp, off); ln += __shfl_down(ln, off); }
  float gold = 0.f;
  if (tid == 0){
    int lt = lb[ln - 1];
    gold = gp + tr[lt*19 + STOP_TAG];
  }
  if (tid < 19) al[tid] = eb[tid] + tr[START_TAG*19 + tid];
  __syncthreads();
  for (int t = 1; t < SS; ++t){
    int m = mb[t];
    float nv = 0.f;
    if (tid < 19){
      float mx = -1e30f;
      for (int p = 0; p < 19; ++p){ float v = al[p] + tr[p*19 + tid]; mx = fmaxf(mx, v); }
      float sum = 0.f;
      for (int p = 0; p < 19; ++p) sum += expf(al[p] + tr[p*19 + tid] - mx);
      nv = mx + logf(sum) + eb[t*19 + tid];
    }
    __syncthreads();
    if (tid < 19 && m) al[tid] = nv;
    __syncthreads();
  }
  if (tid == 0){
    float mx = -1e30f;
    for (int c2 = 0; c2 < 19; ++c2) mx = fmaxf(mx, al[c2] + tr[c2*19 + STOP_TAG]);
    float sum = 0.f;
    for (int c2 = 0; c2 < 19; ++c2) sum += expf(al[c2] + tr[c2*19 + STOP_TAG] - mx);
    nll[b] = (mx + logf(sum)) - gold;
  }
}

// -------- Viterbi decode, one wave per batch; writes tags (as float) to d_out[1..] --------
__global__ void k_vit(const float* __restrict__ emit, const int* __restrict__ msk,
                      const float* __restrict__ trans, int* __restrict__ ptr,
                      float* __restrict__ out){
  int b = blockIdx.x, tid = threadIdx.x;
  __shared__ float tr[361];
  __shared__ float dl[19];
  __shared__ int tg[256];
  for (int i = tid; i < 361; i += 64) tr[i] = trans[i];
  const float* eb = emit + (size_t)b*SS*TT;
  const int* mb = msk + b*SS;
  int* pb = ptr + (size_t)b*SS*TT;
  if (tid < 19) dl[tid] = eb[tid] + tr[START_TAG*19 + tid];
  __syncthreads();
  for (int t = 1; t < SS; ++t){
    int m = mb[t];
    float best = -1e30f; int bp = 0;
    if (tid < 19){
      for (int p = 0; p < 19; ++p){
        float v = dl[p] + tr[p*19 + tid];
        if (v > best){ best = v; bp = p; }       // strict > == first-max (jnp.argmax)
      }
    }
    __syncthreads();
    if (tid < 19){
      if (m){ dl[tid] = best + eb[t*19 + tid]; pb[t*19 + tid] = bp; }
      else  { pb[t*19 + tid] = tid; }            // identity pass-through when padded
    }
    __syncthreads();
  }
  if (tid == 0){
    float bv = -1e30f; int bl = 0;
    for (int c2 = 0; c2 < 19; ++c2){
      float v = dl[c2] + tr[c2*19 + STOP_TAG];
      if (v > bv){ bv = v; bl = c2; }
    }
    tg[SS-1] = bl;
    for (int t = SS-1; t > 0; --t) tg[t-1] = pb[t*19 + tg[t]];
  }
  __syncthreads();
  for (int t = tid; t < SS; t += 64)
    out[1 + b*SS + t] = (float)(tg[t] * mb[t]);
}

// -------- final loss reduce: d_out[0] = sum(nll)/B --------
__global__ void k_final(const float* __restrict__ nll, float* __restrict__ out){
  int tid = threadIdx.x;
  float v = (tid < 32) ? nll[tid] : 0.f;
  for (int off = 32; off; off >>= 1) v += __shfl_down(v, off);
  if (tid == 0) out[0] = v * (1.0f/32.0f);
}

extern "C" void kernel_launch(void* const* d_in, const int* in_sizes, int n_in,
                              void* d_out, int out_size, void* d_ws, size_t ws_size,
                              hipStream_t stream){
  const int*   wi    = (const int*)d_in[0];
  const int*   msk   = (const int*)d_in[1];
  const int*   lab   = (const int*)d_in[2];
  // d_in[3] labels_token, d_in[4] data_type: unused (data_type==1 branch)
  const float* emb   = (const float*)d_in[5];
  const float* Wih_f = (const float*)d_in[6];
  const float* Whh_f = (const float*)d_in[7];
  const float* bih_f = (const float*)d_in[8];
  const float* bhh_f = (const float*)d_in[9];
  const float* Wih_b = (const float*)d_in[10];
  const float* Whh_b = (const float*)d_in[11];
  const float* bih_b = (const float*)d_in[12];
  const float* bhh_b = (const float*)d_in[13];
  const float* Wtag  = (const float*)d_in[14];
  const float* btag  = (const float*)d_in[15];
  const float* trans = (const float*)d_in[16];

  float* ws   = (float*)d_ws;
  float* x    = ws;
  float* xbuf = ws + 2097152;            // inside dead x region (after k_gemm)
  int*   flags= (int*)(ws + 2129920);    // 256 ints, zeroed per launch
  float* WT   = ws + 2490368;
  float* bias = ws + 3112960;
  float4* Wr  = (float4*)(ws + 3115008);
  float* gin  = ws + 3639296;
  float* hseq = ws + 20416512;
  float* emit = ws + 24610816;
  int*   ptr  = (int*)(ws + 24766464);
  float* nll  = ws + 24922112;
  float* out  = (float*)d_out;

  hipLaunchKernelGGL(k_embed,     dim3(2432),    dim3(256),  0, stream, wi, msk, emb, x);
  hipLaunchKernelGGL(k_prep_wt,   dim3(2440),    dim3(256),  0, stream,
                     Wih_f, Wih_b, bih_f, bhh_f, bih_b, bhh_b, WT, bias);
  hipLaunchKernelGGL(k_prep_wreg, dim3(512),     dim3(256),  0, stream, Whh_f, Whh_b, Wr);
  hipLaunchKernelGGL(k_gemm,      dim3(32,128),  dim3(256),  0, stream, x, WT, bias, gin);
  hipMemsetAsync(flags, 0, 256*sizeof(int), stream);
  hipLaunchKernelGGL(k_lstm,      dim3(256),     dim3(1024), 0, stream, gin, Wr, hseq, xbuf, flags);
  hipLaunchKernelGGL(k_emit,      dim3(608),     dim3(256),  0, stream, hseq, Wtag, btag, emit);
  hipLaunchKernelGGL(k_crf,       dim3(32),      dim3(64),   0, stream, emit, msk, lab, trans, nll);
  hipLaunchKernelGGL(k_vit,       dim3(32),      dim3(64),   0, stream, emit, msk, trans, ptr, out);
  hipLaunchKernelGGL(k_final,     dim3(1),       dim3(64),   0, stream, nll, out);
}